// Round 10
// baseline (363.047 us; speedup 1.0000x reference)
//
#include <hip/hip_runtime.h>

#define N_NODES 50000
#define N_EDGES 800000
#define F_NODE 128
#define F_EDGE 16

#define BUCK_SH 6                                // 64 nodes / bucket
#define NBUCK ((N_NODES + 63) >> BUCK_SH)        // 782
#define NPART 8                                  // blockIdx&7 ~ XCD (XCD-local atomics)
#define CAP_PART 304                             // slots per (bucket,part) cell
#define BCUR_STRIDE 16                           // 1 cursor per 64B line
#define CAP_BUCKET 1216                          // fixed CSR stride per bucket (µ=1024, +6σ)

#define CONV_BLOCKS ((N_NODES * 32 + 255) / 256) // 6250 (exact)
#define SCAT_BLOCKS ((N_EDGES + 255) / 256)      // 3125 (exact)
#define NB128 ((N_NODES + 3) / 4)                // 12500 agg128 blocks (4 nodes/blk)
#define NB16  ((N_NODES + 3) / 4)                // 12500 agg16 blocks

#define PERM_T 512                               // permute block size (round-9 verified)

#define KA 160                                   // padded K of the A operand (128+16+16z)
#define WT_PAD 168                               // Wt row stride (16B-aligned, 2-way banks)

// ---------------- bf16 helpers (bf16 = top 16 bits of fp32, RNE) -----------
__device__ __forceinline__ unsigned int bf16_rn(float f) {
    unsigned int u = __float_as_uint(f);
    unsigned int r = ((u >> 16) & 1u) + 0x7fffu;
    return (u + r) >> 16;
}
__device__ __forceinline__ unsigned int pack_bf16(float a, float b) {
    return bf16_rn(a) | (bf16_rn(b) << 16);
}
__device__ __forceinline__ float bf_lo(unsigned int u) { return __uint_as_float(u << 16); }
__device__ __forceinline__ float bf_hi(unsigned int u) { return __uint_as_float(u & 0xffff0000u); }

typedef __attribute__((ext_vector_type(8))) short bf16x8;
typedef __attribute__((ext_vector_type(4))) float f32x4;

// ---------------- fused: x->bf16 convert | bucketed edge scatter -----------
// (round-0 proven) Payload packed: src (17b) | eid (20b) | dst_local (6b).
__global__ __launch_bounds__(256) void convert_and_scatter(
    const float4* __restrict__ x4, uint2* __restrict__ xb2,
    const int* __restrict__ src, const int* __restrict__ dst,
    int* __restrict__ bcur, unsigned long long* __restrict__ temp)
{
    if (blockIdx.x < CONV_BLOCKS) {
        int i = blockIdx.x * 256 + threadIdx.x;     // grid sized exactly
        float4 v = x4[i];
        uint2 o;
        o.x = pack_bf16(v.x, v.y);
        o.y = pack_bf16(v.z, v.w);
        xb2[i] = o;
    } else {
        int e = (int)(blockIdx.x - CONV_BLOCKS) * 256 + threadIdx.x;
        if (e >= N_EDGES) return;
        int d = dst[e];
        int b = d >> BUCK_SH;
        int dl = d & 63;
        int cell = b * NPART + (blockIdx.x & (NPART - 1));
        int pos = atomicAdd(&bcur[cell * BCUR_STRIDE], 1);
        if (pos < CAP_PART)
            temp[(size_t)cell * CAP_PART + pos] =
                (unsigned long long)src[e] |
                ((unsigned long long)e  << 17) |
                ((unsigned long long)dl << 37);
    }
}

// ---------------- CSR build: per-bucket permute + rs2 (round-9 verified) ---
__global__ __launch_bounds__(PERM_T) void bucket_permute(
    const unsigned long long* __restrict__ temp,
    const int* __restrict__ bcur,
    int2* __restrict__ rs2,
    int* __restrict__ csr_src, int* __restrict__ csr_eid)
{
    __shared__ int cnt[64];
    __shared__ int scn[64];
    __shared__ int cnt2[64];
    __shared__ int mm[NPART];
    int b = blockIdx.x;
    int tid = threadIdx.x;
    int node0 = b << BUCK_SH;
    int nn = min(64, N_NODES - node0);
    if (tid < 64) { cnt[tid] = 0; cnt2[tid] = 0; }
    if (tid >= 64 && tid < 64 + NPART) {
        int part = tid - 64;
        int m = bcur[(b * NPART + part) * BCUR_STRIDE];
        mm[part] = m > CAP_PART ? CAP_PART : m;
    }
    __syncthreads();
    const int base = b * CAP_BUCKET;
    const size_t tb0 = (size_t)(b * NPART) * CAP_PART;

    for (int idx = tid; idx < NPART * CAP_PART; idx += PERM_T) {
        int part = idx / CAP_PART;
        int i = idx - part * CAP_PART;
        if (i < mm[part]) {
            int dl = (int)(temp[tb0 + idx] >> 37);
            atomicAdd(&cnt[dl], 1);
        }
    }
    __syncthreads();

    if (tid < 64) scn[tid] = cnt[tid];
    __syncthreads();
    for (int o = 1; o < 64; o <<= 1) {
        int v = 0;
        if (tid < 64 && tid >= o) v = scn[tid - o];
        __syncthreads();
        if (tid < 64) scn[tid] += v;
        __syncthreads();
    }
    if (tid < nn)
        rs2[node0 + tid] = make_int2(base + scn[tid] - cnt[tid], base + scn[tid]);

    for (int idx = tid; idx < NPART * CAP_PART; idx += PERM_T) {
        int part = idx / CAP_PART;
        int i = idx - part * CAP_PART;
        if (i < mm[part]) {
            unsigned long long v = temp[tb0 + idx];
            int s  = (int)(v & 0x1FFFF);
            int ei = (int)((v >> 17) & 0xFFFFF);
            int dl = (int)(v >> 37);
            int pos = base + (scn[dl] - cnt[dl]) + atomicAdd(&cnt2[dl], 1);
            csr_src[pos] = s;
            csr_eid[pos] = ei;
        }
    }
}

// ---------------- agg bodies: gather (round-0 proven) -> bf16 A operand ----
// A16[row][KA=160] bf16: cols 0..127 node-agg, 128..143 edge-agg, 144..159 0.
__device__ __forceinline__ void agg128_body(const unsigned int* __restrict__ xb,
                                            const int2* __restrict__ rs2,
                                            const int* __restrict__ csr_src,
                                            unsigned short* __restrict__ A16,
                                            int bid) {
    int gid = bid * 256 + (int)threadIdx.x;
    int n = gid >> 6;
    int lane = threadIdx.x & 63;
    if (n >= N_NODES) return;
    int2 be = rs2[n];
    int beg = be.x, end = be.y;
    float a0 = 0.f, a1 = 0.f;
    int i = beg;
    for (; i + 8 <= end; i += 8) {
        int s[8];
        #pragma unroll
        for (int t = 0; t < 8; ++t) s[t] = csr_src[i + t];
        unsigned int u[8];
        #pragma unroll
        for (int t = 0; t < 8; ++t) u[t] = xb[(size_t)s[t] * 64 + lane];
        #pragma unroll
        for (int t = 0; t < 8; ++t) { a0 += bf_lo(u[t]); a1 += bf_hi(u[t]); }
    }
    for (; i + 4 <= end; i += 4) {
        int s[4];
        #pragma unroll
        for (int t = 0; t < 4; ++t) s[t] = csr_src[i + t];
        unsigned int u[4];
        #pragma unroll
        for (int t = 0; t < 4; ++t) u[t] = xb[(size_t)s[t] * 64 + lane];
        #pragma unroll
        for (int t = 0; t < 4; ++t) { a0 += bf_lo(u[t]); a1 += bf_hi(u[t]); }
    }
    for (; i < end; ++i) {
        unsigned int u = xb[(size_t)csr_src[i] * 64 + lane];
        a0 += bf_lo(u);
        a1 += bf_hi(u);
    }
    *(unsigned int*)(A16 + (size_t)n * KA + lane * 2) = pack_bf16(a0, a1);
}

__device__ __forceinline__ void agg16_body(const float4* __restrict__ eattr4,
                                           const int2* __restrict__ rs2,
                                           const int* __restrict__ csr_eid,
                                           unsigned short* __restrict__ A16,
                                           int bid) {
    int gid = bid * 256 + (int)threadIdx.x;
    int n = gid >> 6;
    int lane = threadIdx.x & 63;
    int sub = lane >> 2;
    int j4  = lane & 3;
    if (n >= N_NODES) return;
    int2 be = rs2[n];
    int beg = be.x, end = be.y;
    float4 acc = make_float4(0.f, 0.f, 0.f, 0.f);
    for (int i = beg + sub; i < end; i += 16) {
        int eid = csr_eid[i];
        float4 v = eattr4[(size_t)eid * 4 + j4];
        acc.x += v.x; acc.y += v.y; acc.z += v.z; acc.w += v.w;
    }
    #pragma unroll
    for (int m = 4; m <= 32; m <<= 1) {
        acc.x += __shfl_xor(acc.x, m, 64);
        acc.y += __shfl_xor(acc.y, m, 64);
        acc.z += __shfl_xor(acc.z, m, 64);
        acc.w += __shfl_xor(acc.w, m, 64);
    }
    if (sub == 0) {
        *(uint2*)(A16 + (size_t)n * KA + 128 + j4 * 4) =
            make_uint2(pack_bf16(acc.x, acc.y), pack_bf16(acc.z, acc.w));
    } else if (sub == 2) {
        // zero the K-pad tail cols 144..159 (avoid NaN garbage into MFMA)
        *(uint2*)(A16 + (size_t)n * KA + 144 + j4 * 4) = make_uint2(0u, 0u);
    }
}

// layer-1 combo: node-feature gather + edge-attr gather (independent, both
// 0-LDS latency-bound gathers -> share one launch, overlap in flight)
__global__ __launch_bounds__(256) void agg_combo(const unsigned int* __restrict__ xb,
                                                 const float4* __restrict__ eattr4,
                                                 const int2* __restrict__ rs2,
                                                 const int* __restrict__ csr_src,
                                                 const int* __restrict__ csr_eid,
                                                 unsigned short* __restrict__ A16) {
    if (blockIdx.x < NB128)
        agg128_body(xb, rs2, csr_src, A16, blockIdx.x);
    else
        agg16_body(eattr4, rs2, csr_eid, A16, blockIdx.x - NB128);
}

// layer-2 gather only (A16 cols 128..159 persist from layer 1: same eagg+0s)
__global__ __launch_bounds__(256) void agg128_bf16(const unsigned int* __restrict__ xb,
                                                   const int2* __restrict__ rs2,
                                                   const int* __restrict__ csr_src,
                                                   unsigned short* __restrict__ A16) {
    agg128_body(xb, rs2, csr_src, A16, blockIdx.x);
}

// ---------------- bf16 MFMA GEMM -------------------------------------------
// out = A16(N x 160 bf16) @ W(144x128 fp32, zero-padded to 160) + bias.
// Block: 64 rows, 256 thr = 4 waves; wave w owns rows [bm+16w, bm+16w+16),
// 8 n-tiles of 16, K = 5 x 32 via v_mfma_f32_16x16x32_bf16 (fp32 accum).
// Mapping (m89-verified): operands index non-K dim via lane&15, K-group via
// lane>>4 (8 consecutive k); C/D: col=lane&15, row=(lane>>4)*4+r.
// W staged transposed bf16 in LDS: Wt[col][k], row stride 168 u16 (16B-
// aligned, 2-way max bank aliasing = free per m136).
__global__ __launch_bounds__(256) void layer_gemm_mfma(
    const unsigned short* __restrict__ A,   // [N_NODES][KA] bf16
    const float* __restrict__ W,            // [144][128] fp32
    const float* __restrict__ bias,         // [128]
    float* __restrict__ out_f32,            // layer-2 output (d_out)
    unsigned short* __restrict__ out_bf,    // layer-1 output hb u16[row][128]
    int do_relu, int out_bf16)
{
    __shared__ unsigned short Wt[128][WT_PAD];  // 43 KB -> 3 blocks/CU
    const int tid = threadIdx.x;

    // stage W transposed + bf16 (coalesced global reads)
    for (int i = tid; i < 128 * KA; i += 256) {
        int k = i >> 7, col = i & 127;
        float v = (k < 144) ? W[k * 128 + col] : 0.f;
        Wt[col][k] = (unsigned short)bf16_rn(v);
    }
    __syncthreads();

    const int w    = tid >> 6;
    const int lane = tid & 63;
    const int l15  = lane & 15;
    const int kg   = lane >> 4;                  // 0..3 (K-group)
    const int row0 = blockIdx.x * 64 + w * 16;   // wave's 16-row tile
    const int arow = row0 + l15;
    const int rcl  = arow < N_NODES ? arow : N_NODES - 1;

    // all 5 A fragments up front (independent 16B global loads)
    bf16x8 af[5];
    #pragma unroll
    for (int kk = 0; kk < 5; ++kk)
        af[kk] = *(const bf16x8*)(A + (size_t)rcl * KA + kk * 32 + kg * 8);

    f32x4 acc[8];
    #pragma unroll
    for (int nt = 0; nt < 8; ++nt)
        acc[nt] = (f32x4){0.f, 0.f, 0.f, 0.f};

    #pragma unroll
    for (int kk = 0; kk < 5; ++kk) {
        #pragma unroll
        for (int nt = 0; nt < 8; ++nt) {
            bf16x8 bf = *(const bf16x8*)(&Wt[nt * 16 + l15][kk * 32 + kg * 8]);
            acc[nt] = __builtin_amdgcn_mfma_f32_16x16x32_bf16(af[kk], bf, acc[nt], 0, 0, 0);
        }
    }

    // epilogue: C col = l15 (n-tile), row = row0 + kg*4 + r
    #pragma unroll
    for (int nt = 0; nt < 8; ++nt) {
        int col = nt * 16 + l15;
        float bv = bias[col];
        #pragma unroll
        for (int r = 0; r < 4; ++r) {
            int orow = row0 + kg * 4 + r;
            if (orow >= N_NODES) continue;
            float v = acc[nt][r] + bv;
            if (do_relu) v = fmaxf(v, 0.f);
            if (out_bf16)
                out_bf[(size_t)orow * 128 + col] = (unsigned short)bf16_rn(v);
            else
                out_f32[(size_t)orow * 128 + col] = v;
        }
    }
}

// ---------------------------------------------------------------------------
static inline char* align16(char* p) {
    return (char*)(((uintptr_t)p + 15) & ~(uintptr_t)15);
}

extern "C" void kernel_launch(void* const* d_in, const int* in_sizes, int n_in,
                              void* d_out, int out_size, void* d_ws, size_t ws_size,
                              hipStream_t stream) {
    const float* x     = (const float*)d_in[0];   // (50000,128)
    const int*   eidx  = (const int*)  d_in[1];   // (2,800000)
    const float* eattr = (const float*)d_in[2];   // (800000,16)
    const float* W1    = (const float*)d_in[3];   // (144,128)
    const float* b1    = (const float*)d_in[4];
    const float* W2    = (const float*)d_in[5];   // (144,128)
    const float* b2    = (const float*)d_in[6];
    float* out = (float*)d_out;                   // (50000,128)

    const int* srcv = eidx;
    const int* dstv = eidx + N_EDGES;

    // temp lives in d_out: dead before GEMM2 writes out (permute finishes
    // long before; 15.2 MB <= 25.6 MB). Nothing else aliases d_out now.
    unsigned long long* temp = (unsigned long long*)d_out;

    // ws layout (~37.2 MB)
    char* p = (char*)d_ws;
    unsigned int* xbhb   = (unsigned int*)p;   p += (size_t)N_NODES * 64 * 4;         // 12.8 MB
    unsigned short* A16  = (unsigned short*)p; p += (size_t)N_NODES * KA * 2;         // 16.0 MB
    int* csr_src = (int*)p;                 p += (size_t)NBUCK * CAP_BUCKET * 4;      //  3.8 MB
    int* csr_eid = (int*)p;                 p += (size_t)NBUCK * CAP_BUCKET * 4;      //  3.8 MB
    int2* rs2    = (int2*)p;                p += (size_t)N_NODES * 8;                 //  0.4 MB
    p = align16(p);
    int* bcur    = (int*)p;                 p += (size_t)NBUCK * NPART * BCUR_STRIDE * 4; // 400 KB

    // 1. zero cursors
    hipMemsetAsync(bcur, 0, (size_t)NBUCK * NPART * BCUR_STRIDE * 4, stream);

    // 2. bf16 convert | bucket scatter (fused launch, disjoint block ranges)
    convert_and_scatter<<<CONV_BLOCKS + SCAT_BLOCKS, 256, 0, stream>>>(
        (const float4*)x, (uint2*)xbhb, srcv, dstv, bcur, temp);

    // 3. permute into gapped CSR, emit rs2
    bucket_permute<<<NBUCK, PERM_T, 0, stream>>>(temp, bcur, rs2, csr_src, csr_eid);

    // 4. layer-1 gathers: xb -> A16[0:128) | eattr -> A16[128:144) + 0-pad
    agg_combo<<<NB128 + NB16, 256, 0, stream>>>(
        xbhb, (const float4*)eattr, rs2, csr_src, csr_eid, A16);

    // 5. layer-1 GEMM (MFMA): A16 @ W1 + b1, relu -> hb (u16, overwrites xb)
    layer_gemm_mfma<<<(N_NODES + 63) / 64, 256, 0, stream>>>(
        A16, W1, b1, (float*)nullptr, (unsigned short*)xbhb, 1, 1);

    // 6. layer-2 gather: hb -> A16[0:128)  (cols 128..159 persist)
    agg128_bf16<<<NB128, 256, 0, stream>>>(xbhb, rs2, csr_src, A16);

    // 7. layer-2 GEMM (MFMA): A16 @ W2 + b2 -> out (fp32, d_out)
    layer_gemm_mfma<<<(N_NODES + 63) / 64, 256, 0, stream>>>(
        A16, W2, b2, out, (unsigned short*)nullptr, 0, 0);
}

// Round 12
// 273.304 us; speedup vs baseline: 1.3284x; 1.3284x over previous
//
#include <hip/hip_runtime.h>

#define N_NODES 50000
#define N_EDGES 800000
#define F_NODE 128
#define F_EDGE 16

#define BUCK_SH 6                                // 64 nodes / bucket
#define NBUCK ((N_NODES + 63) >> BUCK_SH)        // 782
#define NPART 8                                  // blockIdx&7 ~ XCD (XCD-local atomics)
#define CAP_PART 304                             // slots per (bucket,part) cell
#define BCUR_STRIDE 16                           // 1 cursor per 64B line
#define CAP_BUCKET 1216                          // fixed CSR stride per bucket (µ=1024, +6σ)

#define CONV_BLOCKS ((N_NODES * 32 + 255) / 256) // 6250 (exact)
#define SCAT_BLOCKS ((N_EDGES + 255) / 256)      // 3125 (exact)
#define NB128 ((N_NODES + 3) / 4)                // 12500 agg128 blocks (4 nodes/blk)
#define NB16  ((N_NODES + 3) / 4)                // 12500 agg16 blocks

#define PERM_T 512                               // permute block size (round-9 verified)

#define KA 160                                   // padded K of the A operand (128+16+16z)
#define WT_ELEMS (128 * KA)                      // 20480 u16 per Wt
#define WT_BLOCKS (2 * WT_ELEMS / 256)           // 160 transpose blocks (both W1,W2)

#define RT_TILES ((N_NODES + 15) / 16)           // 3125 row-tiles (exact)
#define GEMM_BLOCKS ((RT_TILES * 2 + 3) / 4)     // 1563 (2 col-halves, 4 waves/blk)

// ---------------- bf16 helpers (bf16 = top 16 bits of fp32, RNE) -----------
__device__ __forceinline__ unsigned int bf16_rn(float f) {
    unsigned int u = __float_as_uint(f);
    unsigned int r = ((u >> 16) & 1u) + 0x7fffu;
    return (u + r) >> 16;
}
__device__ __forceinline__ unsigned int pack_bf16(float a, float b) {
    return bf16_rn(a) | (bf16_rn(b) << 16);
}
__device__ __forceinline__ float bf_lo(unsigned int u) { return __uint_as_float(u << 16); }
__device__ __forceinline__ float bf_hi(unsigned int u) { return __uint_as_float(u & 0xffff0000u); }

typedef __attribute__((ext_vector_type(8))) short bf16x8;
typedef __attribute__((ext_vector_type(4))) float f32x4;

// ---------------- fused: x->bf16 convert | edge scatter | Wt transpose -----
// Blocks [0,CONV): convert x. Blocks [CONV,CONV+SCAT): scatter (round-0
// proven). Blocks [CONV+SCAT, +WT_BLOCKS): build Wt[2][col][k] = bf16
// transpose of W1/W2, K zero-padded to KA (GEMM reads B-fragments directly
// from global -> no LDS staging / conflicts in the GEMM).
__global__ __launch_bounds__(256) void convert_and_scatter(
    const float4* __restrict__ x4, uint2* __restrict__ xb2,
    const int* __restrict__ src, const int* __restrict__ dst,
    int* __restrict__ bcur, unsigned long long* __restrict__ temp,
    const float* __restrict__ W1, const float* __restrict__ W2,
    unsigned short* __restrict__ Wtq)
{
    if (blockIdx.x < CONV_BLOCKS) {
        int i = blockIdx.x * 256 + threadIdx.x;     // grid sized exactly
        float4 v = x4[i];
        uint2 o;
        o.x = pack_bf16(v.x, v.y);
        o.y = pack_bf16(v.z, v.w);
        xb2[i] = o;
    } else if (blockIdx.x < CONV_BLOCKS + SCAT_BLOCKS) {
        int e = (int)(blockIdx.x - CONV_BLOCKS) * 256 + threadIdx.x;
        if (e >= N_EDGES) return;
        int d = dst[e];
        int b = d >> BUCK_SH;
        int dl = d & 63;
        int cell = b * NPART + (blockIdx.x & (NPART - 1));
        int pos = atomicAdd(&bcur[cell * BCUR_STRIDE], 1);
        if (pos < CAP_PART)
            temp[(size_t)cell * CAP_PART + pos] =
                (unsigned long long)src[e] |
                ((unsigned long long)e  << 17) |
                ((unsigned long long)dl << 37);
    } else {
        int idx = (int)(blockIdx.x - CONV_BLOCKS - SCAT_BLOCKS) * 256 + threadIdx.x;
        int sel = idx >= WT_ELEMS;                 // 0 -> W1, 1 -> W2
        int j   = idx - sel * WT_ELEMS;
        int col = j / KA;
        int k   = j - col * KA;
        const float* Wsrc = sel ? W2 : W1;
        float v = (k < 144) ? Wsrc[k * 128 + col] : 0.f;
        Wtq[idx] = (unsigned short)bf16_rn(v);
    }
}

// ---------------- CSR build: per-bucket permute + rs2 (round-9 verified) ---
__global__ __launch_bounds__(PERM_T) void bucket_permute(
    const unsigned long long* __restrict__ temp,
    const int* __restrict__ bcur,
    int2* __restrict__ rs2,
    int* __restrict__ csr_src, int* __restrict__ csr_eid)
{
    __shared__ int cnt[64];
    __shared__ int scn[64];
    __shared__ int cnt2[64];
    __shared__ int mm[NPART];
    int b = blockIdx.x;
    int tid = threadIdx.x;
    int node0 = b << BUCK_SH;
    int nn = min(64, N_NODES - node0);
    if (tid < 64) { cnt[tid] = 0; cnt2[tid] = 0; }
    if (tid >= 64 && tid < 64 + NPART) {
        int part = tid - 64;
        int m = bcur[(b * NPART + part) * BCUR_STRIDE];
        mm[part] = m > CAP_PART ? CAP_PART : m;
    }
    __syncthreads();
    const int base = b * CAP_BUCKET;
    const size_t tb0 = (size_t)(b * NPART) * CAP_PART;

    for (int idx = tid; idx < NPART * CAP_PART; idx += PERM_T) {
        int part = idx / CAP_PART;
        int i = idx - part * CAP_PART;
        if (i < mm[part]) {
            int dl = (int)(temp[tb0 + idx] >> 37);
            atomicAdd(&cnt[dl], 1);
        }
    }
    __syncthreads();

    if (tid < 64) scn[tid] = cnt[tid];
    __syncthreads();
    for (int o = 1; o < 64; o <<= 1) {
        int v = 0;
        if (tid < 64 && tid >= o) v = scn[tid - o];
        __syncthreads();
        if (tid < 64) scn[tid] += v;
        __syncthreads();
    }
    if (tid < nn)
        rs2[node0 + tid] = make_int2(base + scn[tid] - cnt[tid], base + scn[tid]);

    for (int idx = tid; idx < NPART * CAP_PART; idx += PERM_T) {
        int part = idx / CAP_PART;
        int i = idx - part * CAP_PART;
        if (i < mm[part]) {
            unsigned long long v = temp[tb0 + idx];
            int s  = (int)(v & 0x1FFFF);
            int ei = (int)((v >> 17) & 0xFFFFF);
            int dl = (int)(v >> 37);
            int pos = base + (scn[dl] - cnt[dl]) + atomicAdd(&cnt2[dl], 1);
            csr_src[pos] = s;
            csr_eid[pos] = ei;
        }
    }
}

// ---------------- agg bodies: gather (round-0 proven) -> bf16 A operand ----
// A16[row][KA=160] bf16: cols 0..127 node-agg, 128..143 edge-agg, 144..159 0.
__device__ __forceinline__ void agg128_body(const unsigned int* __restrict__ xb,
                                            const int2* __restrict__ rs2,
                                            const int* __restrict__ csr_src,
                                            unsigned short* __restrict__ A16,
                                            int bid) {
    int gid = bid * 256 + (int)threadIdx.x;
    int n = gid >> 6;
    int lane = threadIdx.x & 63;
    if (n >= N_NODES) return;
    int2 be = rs2[n];
    int beg = be.x, end = be.y;
    float a0 = 0.f, a1 = 0.f;
    int i = beg;
    for (; i + 8 <= end; i += 8) {
        int s[8];
        #pragma unroll
        for (int t = 0; t < 8; ++t) s[t] = csr_src[i + t];
        unsigned int u[8];
        #pragma unroll
        for (int t = 0; t < 8; ++t) u[t] = xb[(size_t)s[t] * 64 + lane];
        #pragma unroll
        for (int t = 0; t < 8; ++t) { a0 += bf_lo(u[t]); a1 += bf_hi(u[t]); }
    }
    for (; i + 4 <= end; i += 4) {
        int s[4];
        #pragma unroll
        for (int t = 0; t < 4; ++t) s[t] = csr_src[i + t];
        unsigned int u[4];
        #pragma unroll
        for (int t = 0; t < 4; ++t) u[t] = xb[(size_t)s[t] * 64 + lane];
        #pragma unroll
        for (int t = 0; t < 4; ++t) { a0 += bf_lo(u[t]); a1 += bf_hi(u[t]); }
    }
    for (; i < end; ++i) {
        unsigned int u = xb[(size_t)csr_src[i] * 64 + lane];
        a0 += bf_lo(u);
        a1 += bf_hi(u);
    }
    *(unsigned int*)(A16 + (size_t)n * KA + lane * 2) = pack_bf16(a0, a1);
}

__device__ __forceinline__ void agg16_body(const float4* __restrict__ eattr4,
                                           const int2* __restrict__ rs2,
                                           const int* __restrict__ csr_eid,
                                           unsigned short* __restrict__ A16,
                                           int bid) {
    int gid = bid * 256 + (int)threadIdx.x;
    int n = gid >> 6;
    int lane = threadIdx.x & 63;
    int sub = lane >> 2;
    int j4  = lane & 3;
    if (n >= N_NODES) return;
    int2 be = rs2[n];
    int beg = be.x, end = be.y;
    float4 acc = make_float4(0.f, 0.f, 0.f, 0.f);
    for (int i = beg + sub; i < end; i += 16) {
        int eid = csr_eid[i];
        float4 v = eattr4[(size_t)eid * 4 + j4];
        acc.x += v.x; acc.y += v.y; acc.z += v.z; acc.w += v.w;
    }
    #pragma unroll
    for (int m = 4; m <= 32; m <<= 1) {
        acc.x += __shfl_xor(acc.x, m, 64);
        acc.y += __shfl_xor(acc.y, m, 64);
        acc.z += __shfl_xor(acc.z, m, 64);
        acc.w += __shfl_xor(acc.w, m, 64);
    }
    if (sub == 0) {
        *(uint2*)(A16 + (size_t)n * KA + 128 + j4 * 4) =
            make_uint2(pack_bf16(acc.x, acc.y), pack_bf16(acc.z, acc.w));
    } else if (sub == 2) {
        // zero the K-pad tail cols 144..159 (avoid NaN garbage into MFMA)
        *(uint2*)(A16 + (size_t)n * KA + 144 + j4 * 4) = make_uint2(0u, 0u);
    }
}

// layer-1 combo: node-feature gather + edge-attr gather (independent, both
// 0-LDS latency-bound gathers -> share one launch, overlap in flight)
__global__ __launch_bounds__(256) void agg_combo(const unsigned int* __restrict__ xb,
                                                 const float4* __restrict__ eattr4,
                                                 const int2* __restrict__ rs2,
                                                 const int* __restrict__ csr_src,
                                                 const int* __restrict__ csr_eid,
                                                 unsigned short* __restrict__ A16) {
    if (blockIdx.x < NB128)
        agg128_body(xb, rs2, csr_src, A16, blockIdx.x);
    else
        agg16_body(eattr4, rs2, csr_eid, A16, blockIdx.x - NB128);
}

// layer-2 gather only (A16 cols 128..159 persist from layer 1: same eagg+0s)
__global__ __launch_bounds__(256) void agg128_bf16(const unsigned int* __restrict__ xb,
                                                   const int2* __restrict__ rs2,
                                                   const int* __restrict__ csr_src,
                                                   unsigned short* __restrict__ A16) {
    agg128_body(xb, rs2, csr_src, A16, blockIdx.x);
}

// ---------------- bf16 MFMA GEMM, zero-LDS ---------------------------------
// out = A16(N x 160 bf16) @ Wt^T + bias. B-fragments read DIRECTLY from the
// precomputed global Wt[col][k] (40 KB, L2-resident) -> no LDS staging, no
// barriers, no bank conflicts (round-10 lesson: 2M conflicts, 19% occ).
// One wave per (16-row tile, 64-col half): 6250 waves (2x round-10 TLP),
// 20 MFMAs/wave. Mapping (round-10 verified): operand non-K dim via lane&15,
// K-group via lane>>4; C/D col=lane&15, row=(lane>>4)*4+r.
__global__ __launch_bounds__(256) void layer_gemm_mfma(
    const unsigned short* __restrict__ A,   // [N_NODES][KA] bf16
    const unsigned short* __restrict__ Wt,  // [128][KA] bf16 (transposed, padded)
    const float* __restrict__ bias,         // [128]
    float* __restrict__ out_f32,            // layer-2 output (d_out)
    unsigned short* __restrict__ out_bf,    // layer-1 output hb u16[row][128]
    int do_relu, int out_bf16)
{
    const int tid  = threadIdx.x;
    const int w    = tid >> 6;
    const int lane = tid & 63;
    const int l15  = lane & 15;
    const int kg   = lane >> 4;                  // 0..3 (K-group)

    const int gw   = blockIdx.x * 4 + w;         // global wave id
    const int rt   = gw >> 1;                    // row-tile (16 rows)
    const int ch   = gw & 1;                     // column half (64 cols)
    if (rt >= RT_TILES) return;
    const int row0 = rt * 16;
    const int arow = row0 + l15;
    const int rcl  = arow < N_NODES ? arow : N_NODES - 1;

    // A fragments: 5 x 16B per lane (16 rows x 64B contiguous per instr)
    bf16x8 af[5];
    #pragma unroll
    for (int kk = 0; kk < 5; ++kk)
        af[kk] = *(const bf16x8*)(A + (size_t)rcl * KA + kk * 32 + kg * 8);

    f32x4 acc[4];
    #pragma unroll
    for (int nt = 0; nt < 4; ++nt)
        acc[nt] = (f32x4){0.f, 0.f, 0.f, 0.f};

    #pragma unroll
    for (int kk = 0; kk < 5; ++kk) {
        #pragma unroll
        for (int nt = 0; nt < 4; ++nt) {
            int col = ch * 64 + nt * 16 + l15;
            bf16x8 bf = *(const bf16x8*)(Wt + (size_t)col * KA + kk * 32 + kg * 8);
            acc[nt] = __builtin_amdgcn_mfma_f32_16x16x32_bf16(af[kk], bf, acc[nt], 0, 0, 0);
        }
    }

    // epilogue: C col = ch*64 + nt*16 + l15, row = row0 + kg*4 + r
    #pragma unroll
    for (int nt = 0; nt < 4; ++nt) {
        int col = ch * 64 + nt * 16 + l15;
        float bv = bias[col];
        #pragma unroll
        for (int r = 0; r < 4; ++r) {
            int orow = row0 + kg * 4 + r;
            if (orow >= N_NODES) continue;
            float v = acc[nt][r] + bv;
            if (do_relu) v = fmaxf(v, 0.f);
            if (out_bf16)
                out_bf[(size_t)orow * 128 + col] = (unsigned short)bf16_rn(v);
            else
                out_f32[(size_t)orow * 128 + col] = v;
        }
    }
}

// ---------------------------------------------------------------------------
static inline char* align16(char* p) {
    return (char*)(((uintptr_t)p + 15) & ~(uintptr_t)15);
}

extern "C" void kernel_launch(void* const* d_in, const int* in_sizes, int n_in,
                              void* d_out, int out_size, void* d_ws, size_t ws_size,
                              hipStream_t stream) {
    const float* x     = (const float*)d_in[0];   // (50000,128)
    const int*   eidx  = (const int*)  d_in[1];   // (2,800000)
    const float* eattr = (const float*)d_in[2];   // (800000,16)
    const float* W1    = (const float*)d_in[3];   // (144,128)
    const float* b1    = (const float*)d_in[4];
    const float* W2    = (const float*)d_in[5];   // (144,128)
    const float* b2    = (const float*)d_in[6];
    float* out = (float*)d_out;                   // (50000,128)

    const int* srcv = eidx;
    const int* dstv = eidx + N_EDGES;

    // temp lives in d_out: dead before GEMM2 writes out (permute finishes
    // long before; 15.2 MB <= 25.6 MB). Nothing else aliases d_out.
    unsigned long long* temp = (unsigned long long*)d_out;

    // ws layout (~37.3 MB)
    char* p = (char*)d_ws;
    unsigned int* xbhb   = (unsigned int*)p;   p += (size_t)N_NODES * 64 * 4;         // 12.8 MB
    unsigned short* A16  = (unsigned short*)p; p += (size_t)N_NODES * KA * 2;         // 16.0 MB
    unsigned short* Wtq  = (unsigned short*)p; p += (size_t)2 * WT_ELEMS * 2;         // 80 KB
    int* csr_src = (int*)p;                 p += (size_t)NBUCK * CAP_BUCKET * 4;      //  3.8 MB
    int* csr_eid = (int*)p;                 p += (size_t)NBUCK * CAP_BUCKET * 4;      //  3.8 MB
    int2* rs2    = (int2*)p;                p += (size_t)N_NODES * 8;                 //  0.4 MB
    p = align16(p);
    int* bcur    = (int*)p;                 p += (size_t)NBUCK * NPART * BCUR_STRIDE * 4; // 400 KB

    // 1. zero cursors
    hipMemsetAsync(bcur, 0, (size_t)NBUCK * NPART * BCUR_STRIDE * 4, stream);

    // 2. bf16 convert | bucket scatter | Wt transpose (fused launch)
    convert_and_scatter<<<CONV_BLOCKS + SCAT_BLOCKS + WT_BLOCKS, 256, 0, stream>>>(
        (const float4*)x, (uint2*)xbhb, srcv, dstv, bcur, temp, W1, W2, Wtq);

    // 3. permute into gapped CSR, emit rs2
    bucket_permute<<<NBUCK, PERM_T, 0, stream>>>(temp, bcur, rs2, csr_src, csr_eid);

    // 4. layer-1 gathers: xb -> A16[0:128) | eattr -> A16[128:144) + 0-pad
    agg_combo<<<NB128 + NB16, 256, 0, stream>>>(
        xbhb, (const float4*)eattr, rs2, csr_src, csr_eid, A16);

    // 5. layer-1 GEMM (MFMA, 0-LDS): A16 @ W1 + b1, relu -> hb (u16)
    layer_gemm_mfma<<<GEMM_BLOCKS, 256, 0, stream>>>(
        A16, Wtq, b1, (float*)nullptr, (unsigned short*)xbhb, 1, 1);

    // 6. layer-2 gather: hb -> A16[0:128)  (cols 128..159 persist)
    agg128_bf16<<<NB128, 256, 0, stream>>>(xbhb, rs2, csr_src, A16);

    // 7. layer-2 GEMM (MFMA, 0-LDS): A16 @ W2 + b2 -> out (fp32, d_out)
    layer_gemm_mfma<<<GEMM_BLOCKS, 256, 0, stream>>>(
        A16, Wtq + WT_ELEMS, b2, out, (unsigned short*)nullptr, 0, 0);
}